// Round 1
// baseline (354.510 us; speedup 1.0000x reference)
//
#include <hip/hip_runtime.h>
#include <hip/hip_bf16.h>
#include <stdint.h>

// Problem constants
// N=8, CIN=512, COUT=512, K=3, H=W=64

typedef __attribute__((ext_vector_type(8))) short short8;
typedef __attribute__((ext_vector_type(4))) float f32x4;
typedef __attribute__((ext_vector_type(4))) unsigned int uint4v;

__device__ __forceinline__ unsigned short f2bf(float f) {
  unsigned u = __builtin_bit_cast(unsigned, f);
  u += 0x7FFFu + ((u >> 16) & 1u);   // round-to-nearest-even
  return (unsigned short)(u >> 16);
}

__device__ __forceinline__ void g2l16(const void* g, void* l) {
  __builtin_amdgcn_global_load_lds(
      (const __attribute__((address_space(1))) void*)g,
      (__attribute__((address_space(3))) void*)l, 16, 0, 0);
}

// ---------------- K1: s[n,ci] = style @ mod_weight^T + mod_bias ----------------
__global__ void k_style(const float* __restrict__ style, const float* __restrict__ mw,
                        const float* __restrict__ mb, float* __restrict__ s_out) {
  int t = threadIdx.x;
  int wid = blockIdx.x * 4 + (t >> 6);   // (n,ci) pair, 4096 total
  int lane = t & 63;
  int n = wid >> 9, ci = wid & 511;
  float sum = 0.f;
#pragma unroll
  for (int i = 0; i < 8; ++i) {
    int k = lane + i * 64;
    sum += style[n * 512 + k] * mw[ci * 512 + k];
  }
#pragma unroll
  for (int off = 32; off; off >>= 1) sum += __shfl_xor(sum, off, 64);
  if (lane == 0) s_out[wid] = sum + mb[ci];
}

// ---------------- K2a: wsq[co,ci] = sum_kk conv_w^2 ----------------
__global__ void k_wsq(const float* __restrict__ cw, float* __restrict__ wsq) {
  int id = blockIdx.x * 256 + threadIdx.x;   // (co,ci), 262144 total
  const float* p = cw + (size_t)id * 9;
  float a = 0.f;
#pragma unroll
  for (int j = 0; j < 9; ++j) a += p[j] * p[j];
  wsq[id] = a;
}

// ---------------- K2b: demod[n,co] = rsqrt(sum_ci s^2*wsq + eps) * sqrt2 --------
__global__ void k_demod(const float* __restrict__ s, const float* __restrict__ wsq,
                        float* __restrict__ demod) {
  int t = threadIdx.x;
  int wid = blockIdx.x * 4 + (t >> 6);   // (n,co)
  int lane = t & 63;
  int n = wid >> 9, co = wid & 511;
  float sum = 0.f;
#pragma unroll
  for (int i = 0; i < 8; ++i) {
    int ci = lane + i * 64;
    float sv = s[n * 512 + ci];
    sum += sv * sv * wsq[co * 512 + ci];
  }
#pragma unroll
  for (int off = 32; off; off >>= 1) sum += __shfl_xor(sum, off, 64);
  if (lane == 0) demod[wid] = rsqrtf(sum + 1e-8f) * 1.41421356237309515f;
}

// ---------------- K3: Am[n][cb][kb][tap][cr][ci32] = bf16(cw * s * demod*sqrt2) --
// layout chosen so each (n,cb,kb) tile = 36864 B flat-contiguous = LDS A-tile order
__global__ void k_amod(const float* __restrict__ cw, const float* __restrict__ s,
                       const float* __restrict__ demod, unsigned short* __restrict__ Am) {
  int f = blockIdx.x * 256 + threadIdx.x;  // one thread per 8 bf16 elems
  int c5h = f & 3;
  int f2 = f >> 2;
  int cr = f2 & 63;
  int f3 = f2 >> 6;
  int tap = f3 % 9;
  int f4 = f3 / 9;
  int kb = f4 & 15;
  int f5 = f4 >> 4;
  int cb = f5 & 7;
  int n = f5 >> 3;
  int co = cb * 64 + cr;
  float dm = demod[n * 512 + co];
  unsigned v[8];
#pragma unroll
  for (int j = 0; j < 8; ++j) {
    int ci = kb * 32 + c5h * 8 + j;
    float w = cw[((size_t)co * 512 + ci) * 9 + tap] * s[n * 512 + ci] * dm;
    v[j] = f2bf(w);
  }
  uint4v o;
  o.x = v[0] | (v[1] << 16);
  o.y = v[2] | (v[3] << 16);
  o.z = v[4] | (v[5] << 16);
  o.w = v[6] | (v[7] << 16);
  *(uint4v*)(Am + (size_t)f * 8) = o;
}

// ---------------- K4: x_pad[n][row 66][col 66][ci 512] bf16, zero halo ----------
// transpose (ci inner <-> spatial inner) via LDS tile; pad rows/cols pre-zeroed
__global__ void k_xpad(const float* __restrict__ x, unsigned short* __restrict__ xp) {
  __shared__ unsigned short lds[64][72];
  int t = threadIdx.x;
  int cbn = blockIdx.x;  // ci block (64 ch)
  int h = blockIdx.y;
  int n = blockIdx.z;
  const float* xb = x + (((size_t)n * 512 + cbn * 64) * 64 + h) * 64;
#pragma unroll
  for (int rep = 0; rep < 16; ++rep) {
    int idx = rep * 256 + t;
    int i = idx >> 6, w = idx & 63;
    lds[i][w] = f2bf(xb[(size_t)i * 4096 + w]);
  }
  __syncthreads();
  unsigned short* outb = xp + ((size_t)(n * 66 + h + 1) * 66 + 1) * 512 + cbn * 64;
#pragma unroll
  for (int rep = 0; rep < 2; ++rep) {
    int idx = rep * 256 + t;
    int col = idx >> 3, cig = idx & 7;
    unsigned v[8];
#pragma unroll
    for (int j = 0; j < 8; ++j) v[j] = lds[cig * 8 + j][col];
    uint4v o;
    o.x = v[0] | (v[1] << 16);
    o.y = v[2] | (v[3] << 16);
    o.z = v[4] | (v[5] << 16);
    o.w = v[6] | (v[7] << 16);
    *(uint4v*)(outb + (size_t)col * 512 + cig * 8) = o;
  }
}

// ---------------- K5: implicit-GEMM conv ----------------
// block: 256 thr (4 waves). C-tile: 64 co x (4 rows x 64 cols). K-loop ci, BK=32.
// wave wv handles cols [wv*16, wv*16+16); wave tile 64co x 64pix (4 m-tiles x 4 rows)
__global__ void __launch_bounds__(256, 2) k_conv(
    const unsigned short* __restrict__ Am, const unsigned short* __restrict__ Xp,
    const float* __restrict__ noise, const float* __restrict__ nw_p,
    const float* __restrict__ act_bias, float* __restrict__ out) {
  __shared__ short lds_a[9 * 64 * 32];   // [tap][co_rel][ci32]  36864 B
  __shared__ short lds_x[448 * 32];      // [row 6][col 66][ci32] + slack  28672 B
  int t = threadIdx.x;
  int r0 = blockIdx.x * 4;   // output row block
  int cb = blockIdx.y;       // co block (64)
  int n = blockIdx.z;
  int lane = t & 63, wv = t >> 6;
  int l15 = lane & 15, lhi = lane >> 4;

  // precompute staging source pointers (kb-invariant parts)
  const unsigned short* abase = Am + (size_t)(n * 8 + cb) * 16 * 18432;
  const unsigned short* xg[7];
  int t4 = t >> 2, rem = t & 3;
#pragma unroll
  for (int c = 0; c < 7; ++c) {
    int sl = c * 64 + t4;                 // slot = row*66+col, 396 valid
    int rr = sl / 66, col = sl - rr * 66;
    const unsigned short* g =
        Xp + (size_t)n * 2230272 + (size_t)(r0 + rr) * 33792 + col * 512 + rem * 8;
    if (sl >= 396) g = Xp;                // safe dummy read; LDS slack never read
    xg[c] = g;
  }

  f32x4 acc[4][4];
#pragma unroll
  for (int a = 0; a < 4; ++a)
#pragma unroll
    for (int b = 0; b < 4; ++b) acc[a][b] = (f32x4){0.f, 0.f, 0.f, 0.f};

  const int aoff = l15 * 32 + lhi * 8;            // A frag: m=l&15, k-chunk=(l>>4)*8
  const int xoff = (wv * 16 + l15) * 32 + lhi * 8;

  for (int kb = 0; kb < 16; ++kb) {
    __syncthreads();
    const char* ab = (const char*)(abase + (size_t)kb * 18432);
#pragma unroll
    for (int i = 0; i < 9; ++i)
      g2l16(ab + i * 4096 + t * 16, (char*)lds_a + i * 4096 + t * 16);
#pragma unroll
    for (int c = 0; c < 7; ++c)
      g2l16(xg[c] + kb * 32, (char*)lds_x + c * 4096 + t * 16);
    __syncthreads();

#pragma unroll
    for (int dw = 0; dw < 3; ++dw) {
      short8 bf[6];                       // B frags for tile-rows 0..5 at this dw
#pragma unroll
      for (int rr = 0; rr < 6; ++rr)
        bf[rr] = *(const short8*)(lds_x + rr * 2112 + dw * 32 + xoff);
#pragma unroll
      for (int dh = 0; dh < 3; ++dh) {
#pragma unroll
        for (int mt = 0; mt < 4; ++mt) {
          short8 af = *(const short8*)(lds_a + ((dh * 3 + dw) * 64 + mt * 16) * 32 + aoff);
#pragma unroll
          for (int ri = 0; ri < 4; ++ri)
            acc[mt][ri] =
                __builtin_amdgcn_mfma_f32_16x16x32_bf16(af, bf[ri + dh], acc[mt][ri], 0, 0, 0);
        }
      }
    }
  }

  // epilogue: + noise_weight*noise + act_bias, leaky_relu(0.2). demod*sqrt2 already in A.
  float nw = nw_p[0];
  int col = wv * 16 + l15;
  float nz[4];
#pragma unroll
  for (int ri = 0; ri < 4; ++ri)
    nz[ri] = nw * noise[((size_t)n * 64 + r0 + ri) * 64 + col];
#pragma unroll
  for (int mt = 0; mt < 4; ++mt) {
#pragma unroll
    for (int c = 0; c < 4; ++c) {
      int co = cb * 64 + mt * 16 + lhi * 4 + c;   // C/D row = (lane>>4)*4+reg
      float ab2 = act_bias[co];
#pragma unroll
      for (int ri = 0; ri < 4; ++ri) {
        float v = acc[mt][ri][c] + nz[ri] + ab2;
        v = v > 0.f ? v : 0.2f * v;
        out[(((size_t)n * 512 + co) * 64 + (r0 + ri)) * 64 + col] = v;
      }
    }
  }
}

extern "C" void kernel_launch(void* const* d_in, const int* in_sizes, int n_in,
                              void* d_out, int out_size, void* d_ws, size_t ws_size,
                              hipStream_t stream) {
  const float* x     = (const float*)d_in[0];
  const float* style = (const float*)d_in[1];
  const float* noise = (const float*)d_in[2];
  const float* cw    = (const float*)d_in[3];
  const float* mw    = (const float*)d_in[4];
  const float* mb    = (const float*)d_in[5];
  const float* nw    = (const float*)d_in[6];
  const float* ab    = (const float*)d_in[7];
  float* out = (float*)d_out;

  char* ws = (char*)d_ws;
  float* s_buf  = (float*)ws;                           // 16 KB
  float* demod  = (float*)(ws + 16384);                 // 16 KB
  float* wsq    = (float*)(ws + 32768);                 // 1 MB
  unsigned short* Am = (unsigned short*)(ws + 1081344);   // 37,748,736 B
  unsigned short* Xp = (unsigned short*)(ws + 38830080);  // 35,684,352 B (end ~74.5 MB)

  hipMemsetAsync(Xp, 0, 35684352, stream);              // zero halo for x_pad
  k_style<<<1024, 256, 0, stream>>>(style, mw, mb, s_buf);
  k_wsq<<<1024, 256, 0, stream>>>(cw, wsq);
  k_demod<<<1024, 256, 0, stream>>>(s_buf, wsq, demod);
  k_amod<<<9216, 256, 0, stream>>>(cw, s_buf, demod, Am);
  k_xpad<<<dim3(8, 64, 8), 256, 0, stream>>>(x, Xp);
  k_conv<<<dim3(16, 8, 8), 256, 0, stream>>>(Am, Xp, noise, nw, ab, out);
}

// Round 2
// 285.504 us; speedup vs baseline: 1.2417x; 1.2417x over previous
//
#include <hip/hip_runtime.h>
#include <hip/hip_bf16.h>
#include <stdint.h>

// Problem constants: N=8, CIN=512, COUT=512, K=3, H=W=64

typedef __attribute__((ext_vector_type(8))) short short8;
typedef __attribute__((ext_vector_type(4))) float f32x4;
typedef __attribute__((ext_vector_type(4))) unsigned int uint4v;

__device__ __forceinline__ unsigned short f2bf(float f) {
  unsigned u = __builtin_bit_cast(unsigned, f);
  u += 0x7FFFu + ((u >> 16) & 1u);   // round-to-nearest-even
  return (unsigned short)(u >> 16);
}

__device__ __forceinline__ void g2l16(const void* g, void* l) {
  __builtin_amdgcn_global_load_lds(
      (const __attribute__((address_space(1))) void*)g,
      (__attribute__((address_space(3))) void*)l, 16, 0, 0);
}

// ---------------- P1: fused  s[n,ci] = style@mw^T + mb   |   wsq[co,ci] ----------
__global__ void k_prep1(const float* __restrict__ style, const float* __restrict__ mw,
                        const float* __restrict__ mb, const float* __restrict__ cw,
                        float* __restrict__ s_out, float* __restrict__ wsq) {
  int t = threadIdx.x;
  if (blockIdx.x < 1024) {
    int wid = blockIdx.x * 4 + (t >> 6);   // (n,ci), 4096 total
    int lane = t & 63;
    int n = wid >> 9, ci = wid & 511;
    float sum = 0.f;
#pragma unroll
    for (int i = 0; i < 8; ++i) {
      int k = lane + i * 64;
      sum += style[n * 512 + k] * mw[ci * 512 + k];
    }
#pragma unroll
    for (int off = 32; off; off >>= 1) sum += __shfl_xor(sum, off, 64);
    if (lane == 0) s_out[wid] = sum + mb[ci];
  } else {
    int id = (blockIdx.x - 1024) * 256 + t;   // (co,ci), 262144 total
    const float* p = cw + (size_t)id * 9;
    float a = 0.f;
#pragma unroll
    for (int j = 0; j < 9; ++j) a += p[j] * p[j];
    wsq[id] = a;
  }
}

// ---------------- P2: demod[n,co] = rsqrt(sum_ci s^2*wsq + eps) * sqrt2 ----------
__global__ void k_demod(const float* __restrict__ s, const float* __restrict__ wsq,
                        float* __restrict__ demod) {
  int t = threadIdx.x;
  int wid = blockIdx.x * 4 + (t >> 6);   // (n,co)
  int lane = t & 63;
  int n = wid >> 9, co = wid & 511;
  float sum = 0.f;
#pragma unroll
  for (int i = 0; i < 8; ++i) {
    int ci = lane + i * 64;
    float sv = s[n * 512 + ci];
    sum += sv * sv * wsq[co * 512 + ci];
  }
#pragma unroll
  for (int off = 32; off; off >>= 1) sum += __shfl_xor(sum, off, 64);
  if (lane == 0) demod[wid] = rsqrtf(sum + 1e-8f) * 1.41421356237309515f;
}

// ---------------- P3: fused  Am build (blocks 0..4095)  |  x_pad (4096..8191) ----
// Am[n][cb][kb][tap][cr][ci32] bf16; each (n,cb,kb) tile = 36864 B contiguous.
// x_pad[n][row66][col66][ci512] bf16, halo pre-zeroed by memset.
__global__ void k_prep3(const float* __restrict__ cw, const float* __restrict__ s,
                        const float* __restrict__ demod, const float* __restrict__ x,
                        unsigned short* __restrict__ Am, unsigned short* __restrict__ Xp) {
  __shared__ float smem[5120];   // 20480 B, unioned between the two branches
  int t = threadIdx.x;
  int b = blockIdx.x;
  if (b < 4096) {
    // ---- Am build: one block per (n,co); coalesced cw-row load into LDS ----
    int n = b >> 9, co = b & 511;
    float* wrow = smem;            // 4608 floats: cw row [ci][tap]
    float* srow = smem + 4608;     // 512 floats
    const float* cwr = cw + (size_t)co * 4608;
#pragma unroll
    for (int i = 0; i < 18; ++i) wrow[t + i * 256] = cwr[t + i * 256];
    srow[t]       = s[n * 512 + t];
    srow[t + 256] = s[n * 512 + 256 + t];
    __syncthreads();
    float dm = demod[n * 512 + co];
    int cb = co >> 6, cr = co & 63;
    unsigned short* ob = Am + (size_t)(n * 8 + cb) * 16 * 18432 + cr * 32;
    for (int u = t; u < 576; u += 256) {   // 576 units of 8 shorts
      int kb = u / 36;
      int r = u - kb * 36;
      int tap = r >> 2, q = r & 3;
      unsigned v[8];
#pragma unroll
      for (int j = 0; j < 8; ++j) {
        int ci = kb * 32 + q * 8 + j;
        v[j] = f2bf(wrow[ci * 9 + tap] * srow[ci] * dm);
      }
      uint4v o;
      o.x = v[0] | (v[1] << 16);
      o.y = v[2] | (v[3] << 16);
      o.z = v[4] | (v[5] << 16);
      o.w = v[6] | (v[7] << 16);
      *(uint4v*)(ob + (size_t)kb * 18432 + tap * 2048 + q * 8) = o;
    }
  } else {
    // ---- x transpose+pad: fp32 LDS [64][65] -> 2-way max bank aliasing (free) ----
    b -= 4096;
    int cbn = b & 7, h = (b >> 3) & 63, n = b >> 9;
    float(*lds)[65] = (float(*)[65])smem;   // 64*65*4 = 16640 B
    const float* xb = x + (((size_t)n * 512 + cbn * 64) * 64 + h) * 64;
#pragma unroll
    for (int rep = 0; rep < 16; ++rep) {
      int idx = rep * 256 + t;
      int i = idx >> 6, w = idx & 63;
      lds[i][w] = xb[(size_t)i * 4096 + w];
    }
    __syncthreads();
    unsigned short* outb = Xp + ((size_t)(n * 66 + h + 1) * 66 + 1) * 512 + cbn * 64;
#pragma unroll
    for (int rep = 0; rep < 2; ++rep) {
      int idx = rep * 256 + t;
      int col = idx >> 3, cig = idx & 7;
      unsigned v[8];
#pragma unroll
      for (int j = 0; j < 8; ++j) v[j] = f2bf(lds[cig * 8 + j][col]);
      uint4v o;
      o.x = v[0] | (v[1] << 16);
      o.y = v[2] | (v[3] << 16);
      o.z = v[4] | (v[5] << 16);
      o.w = v[6] | (v[7] << 16);
      *(uint4v*)(outb + (size_t)col * 512 + cig * 8) = o;
    }
  }
}

// ---------------- K5: implicit-GEMM conv, 64co x (8 rows x 64 cols) C-tile -------
// block: 256 thr (4 waves). K-loop ci, BK=32, 16 iters. LDS = 36864+45056 = 80 KiB
// -> exactly 2 blocks/CU. Staged bytes/MFMA = 69 (was 114).
__global__ void __launch_bounds__(256, 2) k_conv(
    const unsigned short* __restrict__ Am, const unsigned short* __restrict__ Xp,
    const float* __restrict__ noise, const float* __restrict__ nw_p,
    const float* __restrict__ act_bias, float* __restrict__ out) {
  __shared__ short lds_a[9 * 64 * 32];   // [tap][co_rel][ci32]  36864 B
  __shared__ short lds_x[11 * 2048];     // [row 10][col 66][ci32] + slack  45056 B
  int t = threadIdx.x;
  int r0 = blockIdx.x * 8;   // output row block (8 rows)
  int cb = blockIdx.y;       // co block (64)
  int n = blockIdx.z;
  int lane = t & 63, wv = t >> 6;
  int l15 = lane & 15, lhi = lane >> 4;

  const unsigned short* abase = Am + (size_t)(n * 8 + cb) * 16 * 18432;
  const unsigned short* xbase = Xp + (size_t)n * 2230272;
  int xoffg[11];
  int t4 = t >> 2, rem = t & 3;
#pragma unroll
  for (int c = 0; c < 11; ++c) {
    int sl = c * 64 + t4;                 // slot = row*66+col, 660 valid
    int rr = sl / 66, col = sl - rr * 66;
    int off = (r0 + rr) * 33792 + col * 512 + rem * 8;
    if (sl >= 660) off = 0;               // dummy read; LDS slack never read
    xoffg[c] = off;
  }

  f32x4 acc[4][8];
#pragma unroll
  for (int a = 0; a < 4; ++a)
#pragma unroll
    for (int b = 0; b < 8; ++b) acc[a][b] = (f32x4){0.f, 0.f, 0.f, 0.f};

  const int aoff = l15 * 32 + lhi * 8;            // A frag: m=l&15, k-chunk=(l>>4)*8
  const int xoff = (wv * 16 + l15) * 32 + lhi * 8;

  for (int kb = 0; kb < 16; ++kb) {
    __syncthreads();
    const char* ab = (const char*)(abase + (size_t)kb * 18432);
#pragma unroll
    for (int i = 0; i < 9; ++i)
      g2l16(ab + i * 4096 + t * 16, (char*)lds_a + i * 4096 + t * 16);
#pragma unroll
    for (int c = 0; c < 11; ++c)
      g2l16(xbase + xoffg[c] + kb * 32, (char*)lds_x + c * 4096 + t * 16);
    __syncthreads();

#pragma unroll
    for (int dw = 0; dw < 3; ++dw) {
      short8 bf[10];                      // B frags rows 0..9 at this dw (shared by dh)
#pragma unroll
      for (int rr = 0; rr < 10; ++rr)
        bf[rr] = *(const short8*)(lds_x + rr * 2112 + dw * 32 + xoff);
#pragma unroll
      for (int dh = 0; dh < 3; ++dh) {
#pragma unroll
        for (int mt = 0; mt < 4; ++mt) {
          short8 af = *(const short8*)(lds_a + ((dh * 3 + dw) * 64 + mt * 16) * 32 + aoff);
#pragma unroll
          for (int ri = 0; ri < 8; ++ri)
            acc[mt][ri] =
                __builtin_amdgcn_mfma_f32_16x16x32_bf16(af, bf[ri + dh], acc[mt][ri], 0, 0, 0);
        }
      }
    }
  }

  // epilogue: + noise_weight*noise + act_bias, leaky_relu(0.2). demod*sqrt2 in A.
  float nw = nw_p[0];
  int col = wv * 16 + l15;
  float nz[8];
#pragma unroll
  for (int ri = 0; ri < 8; ++ri)
    nz[ri] = nw * noise[((size_t)n * 64 + r0 + ri) * 64 + col];
#pragma unroll
  for (int mt = 0; mt < 4; ++mt) {
#pragma unroll
    for (int c = 0; c < 4; ++c) {
      int co = cb * 64 + mt * 16 + lhi * 4 + c;   // C/D row = (lane>>4)*4+reg
      float ab2 = act_bias[co];
#pragma unroll
      for (int ri = 0; ri < 8; ++ri) {
        float v = acc[mt][ri][c] + nz[ri] + ab2;
        v = v > 0.f ? v : 0.2f * v;
        out[(((size_t)n * 512 + co) * 64 + (r0 + ri)) * 64 + col] = v;
      }
    }
  }
}

extern "C" void kernel_launch(void* const* d_in, const int* in_sizes, int n_in,
                              void* d_out, int out_size, void* d_ws, size_t ws_size,
                              hipStream_t stream) {
  const float* x     = (const float*)d_in[0];
  const float* style = (const float*)d_in[1];
  const float* noise = (const float*)d_in[2];
  const float* cw    = (const float*)d_in[3];
  const float* mw    = (const float*)d_in[4];
  const float* mb    = (const float*)d_in[5];
  const float* nw    = (const float*)d_in[6];
  const float* ab    = (const float*)d_in[7];
  float* out = (float*)d_out;

  char* ws = (char*)d_ws;
  float* s_buf  = (float*)ws;                           // 16 KB
  float* demod  = (float*)(ws + 16384);                 // 16 KB
  float* wsq    = (float*)(ws + 32768);                 // 1 MB
  unsigned short* Am = (unsigned short*)(ws + 1081344);   // 37,748,736 B
  unsigned short* Xp = (unsigned short*)(ws + 38830080);  // 35,684,352 B (end ~74.5 MB)

  hipMemsetAsync(Xp, 0, 35684352, stream);              // zero halo for x_pad
  k_prep1<<<2048, 256, 0, stream>>>(style, mw, mb, cw, s_buf, wsq);
  k_demod<<<1024, 256, 0, stream>>>(s_buf, wsq, demod);
  k_prep3<<<8192, 256, 0, stream>>>(cw, s_buf, demod, x, Am, Xp);
  k_conv<<<dim3(8, 8, 8), 256, 0, stream>>>(Am, Xp, noise, nw, ab, out);
}

// Round 3
// 279.993 us; speedup vs baseline: 1.2661x; 1.0197x over previous
//
#include <hip/hip_runtime.h>
#include <hip/hip_bf16.h>
#include <stdint.h>

// Problem constants: N=8, CIN=512, COUT=512, K=3, H=W=64
// Decomposition: out = demod[n,co]*sqrt2 * conv(cw, s[n,ci]*x) + nw*noise + bias, leaky
//   (s folded into input, demod into epilogue -> weights shared across n)

typedef __attribute__((ext_vector_type(8))) short short8;
typedef __attribute__((ext_vector_type(4))) float f32x4;
typedef __attribute__((ext_vector_type(4))) unsigned int uint4v;

__device__ __forceinline__ unsigned short f2bf(float f) {
  unsigned u = __builtin_bit_cast(unsigned, f);
  u += 0x7FFFu + ((u >> 16) & 1u);   // round-to-nearest-even
  return (unsigned short)(u >> 16);
}

__device__ __forceinline__ void g2l16(const void* g, void* l) {
  __builtin_amdgcn_global_load_lds(
      (const __attribute__((address_space(1))) void*)g,
      (__attribute__((address_space(3))) void*)l, 16, 0, 0);
}

// ---------------- P1: style GEMV | wsq | Wt build (fused, independent) ----------
// Wt layout: [cb 8][kb 16]{ [tap 9][mt 4][lhi 4][m 16][ci8 8] } bf16  (4.72 MB)
//   co = cb*64+mt*16+m, ci = kb*32+lhi*8+j. Tile (cb,kb) = 36864 B contiguous,
//   fragment-ordered so conv-side ds_read_b128 is conflict-free.
__global__ void k_prep1(const float* __restrict__ style, const float* __restrict__ mw,
                        const float* __restrict__ mb, const float* __restrict__ cw,
                        float* __restrict__ s_out, float* __restrict__ wsq,
                        unsigned short* __restrict__ Wt) {
  __shared__ float ldsf[18432];   // 72 KiB (Wt branch only)
  int t = threadIdx.x;
  int b = blockIdx.x;
  if (b < 1024) {
    int wid = b * 4 + (t >> 6);   // (n,ci), 4096 total
    int lane = t & 63;
    int n = wid >> 9, ci = wid & 511;
    float sum = 0.f;
#pragma unroll
    for (int i = 0; i < 8; ++i) {
      int k = lane + i * 64;
      sum += style[n * 512 + k] * mw[ci * 512 + k];
    }
#pragma unroll
    for (int off = 32; off; off >>= 1) sum += __shfl_xor(sum, off, 64);
    if (lane == 0) s_out[wid] = sum + mb[ci];
  } else if (b < 2048) {
    int id = (b - 1024) * 256 + t;   // (co,ci), 262144 total
    const float* p = cw + (size_t)id * 9;
    float a = 0.f;
#pragma unroll
    for (int j = 0; j < 9; ++j) a += p[j] * p[j];
    wsq[id] = a;
  } else {
    // ---- Wt: one block per (cb,kb) tile ----
    int bb = b - 2048;
    int cb = bb >> 4, kb = bb & 15;
    // stage cw[co in cb*64..+64][ci in kb*32..+32][tap 9] = 64 segs x 288 floats
#pragma unroll
    for (int i = 0; i < 72; ++i) {
      int idx = t + i * 256;
      int seg = idx / 288, off = idx - seg * 288;
      ldsf[idx] = cw[(size_t)(cb * 64 + seg) * 4608 + kb * 288 + off];
    }
    __syncthreads();
    unsigned short* ob = Wt + (size_t)(cb * 16 + kb) * 18432;
#pragma unroll
    for (int i = 0; i < 9; ++i) {
      int c = t + i * 256;          // chunk 0..2303
      int m = c & 15, lhi = (c >> 4) & 3, mt = (c >> 6) & 3, tap = c >> 8;
      int co_rel = mt * 16 + m;
      unsigned v[8];
#pragma unroll
      for (int j = 0; j < 8; ++j)
        v[j] = f2bf(ldsf[co_rel * 288 + (lhi * 8 + j) * 9 + tap]);
      uint4v o;
      o.x = v[0] | (v[1] << 16);
      o.y = v[2] | (v[3] << 16);
      o.z = v[4] | (v[5] << 16);
      o.w = v[6] | (v[7] << 16);
      *(uint4v*)(ob + (size_t)c * 8) = o;
    }
  }
}

// ---------------- P2: demod (blocks 0..1023) | xpad with s-modulation -----------
// Xp layout: [n 8][row 66][kb 16][lhi 4][col 66][8] bf16, halo zero (memset).
__global__ void k_prep2(const float* __restrict__ s, const float* __restrict__ wsq,
                        const float* __restrict__ x, float* __restrict__ demod,
                        unsigned short* __restrict__ Xp) {
  __shared__ float smem[4225];   // [64][65] + s row slack handled separately
  __shared__ float sx[64];
  int t = threadIdx.x;
  int b = blockIdx.x;
  if (b < 1024) {
    int wid = b * 4 + (t >> 6);   // (n,co)
    int lane = t & 63;
    int n = wid >> 9, co = wid & 511;
    float sum = 0.f;
#pragma unroll
    for (int i = 0; i < 8; ++i) {
      int ci = lane + i * 64;
      float sv = s[n * 512 + ci];
      sum += sv * sv * wsq[co * 512 + ci];
    }
#pragma unroll
    for (int off = 32; off; off >>= 1) sum += __shfl_xor(sum, off, 64);
    if (lane == 0) demod[wid] = rsqrtf(sum + 1e-8f) * 1.41421356237309515f;
  } else {
    int b2 = b - 1024;
    int cbn = b2 & 7, h = (b2 >> 3) & 63, n = b2 >> 9;
    float(*lds)[65] = (float(*)[65])smem;
    const float* xb = x + (((size_t)n * 512 + cbn * 64) * 64 + h) * 64;
#pragma unroll
    for (int rep = 0; rep < 16; ++rep) {
      int idx = rep * 256 + t;
      int i = idx >> 6, w = idx & 63;
      lds[i][w] = xb[(size_t)i * 4096 + w];
    }
    if (t < 64) sx[t] = s[n * 512 + cbn * 64 + t];
    __syncthreads();
    // write: chunk c = rep*256+t; cig = c>>6 (ci group of 8), col = c&63
    // 64-lane groups share cig -> 64 consecutive 16B chunks (coalesced 1 KiB)
    unsigned short* nb = Xp + (size_t)n * 2230272 + (size_t)(h + 1) * 33792;
#pragma unroll
    for (int rep = 0; rep < 2; ++rep) {
      int c = rep * 256 + t;
      int cig = c >> 6, col = c & 63;
      int kb = cbn * 2 + (cig >> 2), lhi = cig & 3;
      unsigned v[8];
#pragma unroll
      for (int j = 0; j < 8; ++j) v[j] = f2bf(lds[cig * 8 + j][col] * sx[cig * 8 + j]);
      uint4v o;
      o.x = v[0] | (v[1] << 16);
      o.y = v[2] | (v[3] << 16);
      o.z = v[4] | (v[5] << 16);
      o.w = v[6] | (v[7] << 16);
      *(uint4v*)(nb + ((size_t)(kb * 4 + lhi) * 66 + col + 1) * 8) = o;
    }
  }
}

// ---------------- K5: implicit-GEMM conv, 64co x (8 rows x 64 cols) C-tile -------
// LDS A: [tap 9][mt 4][lhi 4][m 16][8]  36864 B ; LDS X: [row 10][lhi 4][col 66][8]
// 42240 B (+slack to 45056). Both fragment-ordered -> conflict-free ds_read_b128.
__global__ void __launch_bounds__(256, 2) k_conv(
    const unsigned short* __restrict__ Wt, const unsigned short* __restrict__ Xp,
    const float* __restrict__ demod, const float* __restrict__ noise,
    const float* __restrict__ nw_p, const float* __restrict__ act_bias,
    float* __restrict__ out) {
  __shared__ short lds_a[18432];   // 36864 B
  __shared__ short lds_x[22528];   // 45056 B (42240 used + staging slack)
  int t = threadIdx.x;
  int r0 = blockIdx.x * 8;   // output row block (8 rows)
  int cb = blockIdx.y;       // co block (64)
  int n = blockIdx.z;
  int lane = t & 63, wv = t >> 6;
  int l15 = lane & 15, lhi = lane >> 4;

  const unsigned short* abase = Wt + (size_t)cb * 16 * 18432;
  const unsigned short* xbase = Xp + (size_t)n * 2230272;
  // X staging: 2640 valid 16B chunks = 10 rows x 264; chunk c = j*256+t
  int xoffg[11];
#pragma unroll
  for (int j = 0; j < 11; ++j) {
    int c = j * 256 + t;
    int r = c / 264, rc = c - r * 264;
    int off = (r0 + r) * 33792 + rc * 8;
    if (c >= 2640) off = 0;   // dummy read; lands in LDS slack, never read
    xoffg[j] = off;
  }

  f32x4 acc[4][8];
#pragma unroll
  for (int a = 0; a < 4; ++a)
#pragma unroll
    for (int bq = 0; bq < 8; ++bq) acc[a][bq] = (f32x4){0.f, 0.f, 0.f, 0.f};

  const int aoff = lhi * 128 + l15 * 8;          // A frag: [lhi][m][8]
  const int xoffb = lhi * 528 + (wv * 16 + l15) * 8;   // X frag: [lhi][col][8]

  for (int kb = 0; kb < 16; ++kb) {
    __syncthreads();
    const char* ab = (const char*)(abase + (size_t)kb * 18432);
#pragma unroll
    for (int i = 0; i < 9; ++i)
      g2l16(ab + i * 4096 + t * 16, (char*)lds_a + i * 4096 + t * 16);
#pragma unroll
    for (int j = 0; j < 11; ++j)
      g2l16(xbase + xoffg[j] + kb * 2112, (char*)lds_x + j * 4096 + t * 16);
    __syncthreads();

#pragma unroll
    for (int dw = 0; dw < 3; ++dw) {
      short8 bf[10];   // B frags rows 0..9 at this dw (shared across dh)
#pragma unroll
      for (int rr = 0; rr < 10; ++rr)
        bf[rr] = *(const short8*)(lds_x + rr * 2112 + dw * 8 + xoffb);
#pragma unroll
      for (int dh = 0; dh < 3; ++dh) {
#pragma unroll
        for (int mt = 0; mt < 4; ++mt) {
          short8 af = *(const short8*)(lds_a + (dh * 3 + dw) * 2048 + mt * 512 + aoff);
#pragma unroll
          for (int ri = 0; ri < 8; ++ri)
            acc[mt][ri] =
                __builtin_amdgcn_mfma_f32_16x16x32_bf16(af, bf[ri + dh], acc[mt][ri], 0, 0, 0);
        }
      }
    }
  }

  // epilogue: demod*sqrt2 scale, + noise_weight*noise + act_bias, leaky_relu(0.2)
  float nw = nw_p[0];
  int col = wv * 16 + l15;
  float nz[8];
#pragma unroll
  for (int ri = 0; ri < 8; ++ri)
    nz[ri] = nw * noise[((size_t)n * 64 + r0 + ri) * 64 + col];
#pragma unroll
  for (int mt = 0; mt < 4; ++mt) {
    f32x4 dm4 = *(const f32x4*)(demod + n * 512 + cb * 64 + mt * 16 + lhi * 4);
#pragma unroll
    for (int c = 0; c < 4; ++c) {
      int co = cb * 64 + mt * 16 + lhi * 4 + c;   // C/D row = (lane>>4)*4+reg
      float ab2 = act_bias[co];
      float dm = dm4[c];
#pragma unroll
      for (int ri = 0; ri < 8; ++ri) {
        float v = dm * acc[mt][ri][c] + nz[ri] + ab2;
        v = v > 0.f ? v : 0.2f * v;
        out[(((size_t)n * 512 + co) * 64 + (r0 + ri)) * 64 + col] = v;
      }
    }
  }
}

extern "C" void kernel_launch(void* const* d_in, const int* in_sizes, int n_in,
                              void* d_out, int out_size, void* d_ws, size_t ws_size,
                              hipStream_t stream) {
  const float* x     = (const float*)d_in[0];
  const float* style = (const float*)d_in[1];
  const float* noise = (const float*)d_in[2];
  const float* cw    = (const float*)d_in[3];
  const float* mw    = (const float*)d_in[4];
  const float* mb    = (const float*)d_in[5];
  const float* nw    = (const float*)d_in[6];
  const float* ab    = (const float*)d_in[7];
  float* out = (float*)d_out;

  char* ws = (char*)d_ws;
  float* s_buf  = (float*)ws;                            // 16 KB
  float* demod  = (float*)(ws + 16384);                  // 16 KB
  float* wsq    = (float*)(ws + 32768);                  // 1 MB
  unsigned short* Wt = (unsigned short*)(ws + 1081344);  // 4,718,592 B
  unsigned short* Xp = (unsigned short*)(ws + 5799936);  // 35,684,352 B (end 41.5 MB)

  hipMemsetAsync(Xp, 0, 35684352, stream);               // zero halo for x_pad
  k_prep1<<<2176, 256, 0, stream>>>(style, mw, mb, cw, s_buf, wsq, Wt);
  k_prep2<<<5120, 256, 0, stream>>>(s_buf, wsq, x, demod, Xp);
  k_conv<<<dim3(8, 8, 8), 256, 0, stream>>>(Wt, Xp, demod, noise, nw, ab, out);
}

// Round 4
// 273.029 us; speedup vs baseline: 1.2984x; 1.0255x over previous
//
#include <hip/hip_runtime.h>
#include <hip/hip_bf16.h>
#include <stdint.h>

// Problem constants: N=8, CIN=512, COUT=512, K=3, H=W=64
// out = demod[n,co]*sqrt2 * conv(cw, s[n,ci]*x) + nw*noise + bias, leaky(0.2)

typedef __attribute__((ext_vector_type(8))) short short8;
typedef __attribute__((ext_vector_type(4))) float f32x4;
typedef __attribute__((ext_vector_type(4))) unsigned int uint4v;
typedef __attribute__((ext_vector_type(2))) unsigned int uint2v;

__device__ __forceinline__ unsigned short f2bf(float f) {
  unsigned u = __builtin_bit_cast(unsigned, f);
  u += 0x7FFFu + ((u >> 16) & 1u);   // round-to-nearest-even
  return (unsigned short)(u >> 16);
}

__device__ __forceinline__ void g2l16(const void* g, void* l) {
  __builtin_amdgcn_global_load_lds(
      (const __attribute__((address_space(1))) void*)g,
      (__attribute__((address_space(3))) void*)l, 16, 0, 0);
}

// ---------------- k_pre: style GEMV (0..1023) | wsq (1024..2047) ----------------
__global__ void k_pre(const float* __restrict__ style, const float* __restrict__ mw,
                      const float* __restrict__ mb, const float* __restrict__ cw,
                      float* __restrict__ s_out, float* __restrict__ wsq) {
  int t = threadIdx.x;
  int b = blockIdx.x;
  if (b < 1024) {
    int wid = b * 4 + (t >> 6);   // (n,ci), 4096 total
    int lane = t & 63;
    int n = wid >> 9, ci = wid & 511;
    float sum = 0.f;
#pragma unroll
    for (int i = 0; i < 8; ++i) {
      int k = lane + i * 64;
      sum += style[n * 512 + k] * mw[ci * 512 + k];
    }
#pragma unroll
    for (int off = 32; off; off >>= 1) sum += __shfl_xor(sum, off, 64);
    if (lane == 0) s_out[wid] = sum + mb[ci];
  } else {
    int id = (b - 1024) * 256 + t;   // (co,ci), 262144 total
    const float* p = cw + (size_t)id * 9;
    float a = 0.f;
#pragma unroll
    for (int j = 0; j < 9; ++j) a += p[j] * p[j];
    wsq[id] = a;
  }
}

// ---------------- k_mid: xpad(0..511) | demod(512..1535) | Wt(1536..1663) | halo --
// Xp layout: [n 8][row 66][kb 16][lhi 4][col 66][8] bf16.
// Wt layout: [cb 8][kb 16]{ [tap 9][mt 4][lhi 4][m 16][8] } bf16, tile 36864 B.
__global__ void k_mid(const float* __restrict__ s, const float* __restrict__ wsq,
                      const float* __restrict__ x, const float* __restrict__ cw,
                      float* __restrict__ demod, unsigned short* __restrict__ Xp,
                      unsigned short* __restrict__ Wt) {
  __shared__ char smem[74240];
  int t = threadIdx.x;
  int b = blockIdx.x;
  if (b < 512) {
    // ---- xpad: block (n,h): all 512 ci, 64 cols. float4 loads, bf16 LDS tile ----
    int n = b >> 6, h = b & 63;
    short* ldsx = (short*)smem;              // [ci 512][68]  69632 B
    float* sxf = (float*)(smem + 69632);     // [512]
    sxf[t] = s[n * 512 + t];
    sxf[t + 256] = s[n * 512 + 256 + t];
    __syncthreads();
    const float* xb = x + ((size_t)n * 512) * 4096 + h * 64;
#pragma unroll
    for (int i = 0; i < 32; ++i) {
      int L = t + i * 256;
      int ci = L >> 4, q = L & 15;
      f32x4 v = *(const f32x4*)(xb + (size_t)ci * 4096 + q * 4);
      float sv = sxf[ci];
      uint2v o;
      o.x = f2bf(v.x * sv) | ((unsigned)f2bf(v.y * sv) << 16);
      o.y = f2bf(v.z * sv) | ((unsigned)f2bf(v.w * sv) << 16);
      *(uint2v*)(ldsx + ci * 68 + q * 4) = o;
    }
    __syncthreads();
    unsigned short* nb = Xp + (size_t)n * 2230272 + (size_t)(h + 1) * 33792;
#pragma unroll
    for (int r = 0; r < 16; ++r) {
      int u = t + r * 256;
      int cig = u >> 6, col = u & 63;   // cig = kb*4+lhi (ci = cig*8+j)
      unsigned v[8];
#pragma unroll
      for (int j = 0; j < 8; ++j)
        v[j] = (unsigned short)ldsx[(cig * 8 + j) * 68 + col];
      uint4v o;
      o.x = v[0] | (v[1] << 16);
      o.y = v[2] | (v[3] << 16);
      o.z = v[4] | (v[5] << 16);
      o.w = v[6] | (v[7] << 16);
      *(uint4v*)(nb + ((size_t)cig * 66 + col + 1) * 8) = o;
    }
  } else if (b < 1536) {
    // ---- demod ----
    int wid = (b - 512) * 4 + (t >> 6);   // (n,co)
    int lane = t & 63;
    int n = wid >> 9, co = wid & 511;
    float sum = 0.f;
#pragma unroll
    for (int i = 0; i < 8; ++i) {
      int ci = lane + i * 64;
      float sv = s[n * 512 + ci];
      sum += sv * sv * wsq[co * 512 + ci];
    }
#pragma unroll
    for (int off = 32; off; off >>= 1) sum += __shfl_xor(sum, off, 64);
    if (lane == 0) demod[wid] = rsqrtf(sum + 1e-8f) * 1.41421356237309515f;
  } else if (b < 1664) {
    // ---- Wt build: one block per (cb,kb); LDS stride 289 -> conflict-free ----
    int bb = b - 1536;
    int cb = bb >> 4, kb = bb & 15;
    float* ldsf = (float*)smem;   // [64][289]  73984 B
#pragma unroll
    for (int i = 0; i < 72; ++i) {
      int idx = t + i * 256;
      int seg = idx / 288, off = idx - seg * 288;
      ldsf[seg * 289 + off] = cw[(size_t)(cb * 64 + seg) * 4608 + kb * 288 + off];
    }
    __syncthreads();
    unsigned short* ob = Wt + (size_t)(cb * 16 + kb) * 18432;
#pragma unroll
    for (int i = 0; i < 9; ++i) {
      int c = t + i * 256;   // chunk 0..2303
      int m = c & 15, lhi = (c >> 4) & 3, mt = (c >> 6) & 3, tap = c >> 8;
      int co_rel = mt * 16 + m;
      unsigned v[8];
#pragma unroll
      for (int j = 0; j < 8; ++j)
        v[j] = f2bf(ldsf[co_rel * 289 + (lhi * 8 + j) * 9 + tap]);
      uint4v o;
      o.x = v[0] | (v[1] << 16);
      o.y = v[2] | (v[3] << 16);
      o.z = v[4] | (v[5] << 16);
      o.w = v[6] | (v[7] << 16);
      *(uint4v*)(ob + (size_t)c * 8) = o;
    }
  } else {
    // ---- halo zero: 16640 16B-chunks per n; 17 parts x 1024 chunks ----
    int bb = b - 1664;
    int n = bb / 17, part = bb % 17;
    uint4v z = (uint4v){0u, 0u, 0u, 0u};
    unsigned short* base = Xp + (size_t)n * 2230272;
#pragma unroll
    for (int i = 0; i < 4; ++i) {
      int id = part * 1024 + i * 256 + t;
      if (id < 16640) {
        size_t off;
        if (id < 8448) {                 // rows 0 and 65, full rows
          int row = (id < 4224) ? 0 : 65;
          int c = id - ((id < 4224) ? 0 : 4224);
          off = (size_t)row * 33792 + (size_t)c * 8;
        } else {                         // cols 0 and 65, rows 1..64
          int id2 = id - 8448;
          int row = 1 + (id2 >> 7);
          int rem = id2 & 127;
          int klhi = rem >> 1;
          int col = (rem & 1) ? 65 : 0;
          off = (size_t)row * 33792 + ((size_t)klhi * 66 + col) * 8;
        }
        *(uint4v*)(base + off) = z;
      }
    }
  }
}

// ---------------- k_conv: implicit-GEMM conv (UNCHANGED from R3) -----------------
__global__ void __launch_bounds__(256, 2) k_conv(
    const unsigned short* __restrict__ Wt, const unsigned short* __restrict__ Xp,
    const float* __restrict__ demod, const float* __restrict__ noise,
    const float* __restrict__ nw_p, const float* __restrict__ act_bias,
    float* __restrict__ out) {
  __shared__ short lds_a[18432];   // 36864 B
  __shared__ short lds_x[22528];   // 45056 B (42240 used + staging slack)
  int t = threadIdx.x;
  int r0 = blockIdx.x * 8;
  int cb = blockIdx.y;
  int n = blockIdx.z;
  int lane = t & 63, wv = t >> 6;
  int l15 = lane & 15, lhi = lane >> 4;

  const unsigned short* abase = Wt + (size_t)cb * 16 * 18432;
  const unsigned short* xbase = Xp + (size_t)n * 2230272;
  int xoffg[11];
#pragma unroll
  for (int j = 0; j < 11; ++j) {
    int c = j * 256 + t;
    int r = c / 264, rc = c - r * 264;
    int off = (r0 + r) * 33792 + rc * 8;
    if (c >= 2640) off = 0;
    xoffg[j] = off;
  }

  f32x4 acc[4][8];
#pragma unroll
  for (int a = 0; a < 4; ++a)
#pragma unroll
    for (int bq = 0; bq < 8; ++bq) acc[a][bq] = (f32x4){0.f, 0.f, 0.f, 0.f};

  const int aoff = lhi * 128 + l15 * 8;
  const int xoffb = lhi * 528 + (wv * 16 + l15) * 8;

  for (int kb = 0; kb < 16; ++kb) {
    __syncthreads();
    const char* ab = (const char*)(abase + (size_t)kb * 18432);
#pragma unroll
    for (int i = 0; i < 9; ++i)
      g2l16(ab + i * 4096 + t * 16, (char*)lds_a + i * 4096 + t * 16);
#pragma unroll
    for (int j = 0; j < 11; ++j)
      g2l16(xbase + xoffg[j] + kb * 2112, (char*)lds_x + j * 4096 + t * 16);
    __syncthreads();

#pragma unroll
    for (int dw = 0; dw < 3; ++dw) {
      short8 bf[10];
#pragma unroll
      for (int rr = 0; rr < 10; ++rr)
        bf[rr] = *(const short8*)(lds_x + rr * 2112 + dw * 8 + xoffb);
#pragma unroll
      for (int dh = 0; dh < 3; ++dh) {
#pragma unroll
        for (int mt = 0; mt < 4; ++mt) {
          short8 af = *(const short8*)(lds_a + (dh * 3 + dw) * 2048 + mt * 512 + aoff);
#pragma unroll
          for (int ri = 0; ri < 8; ++ri)
            acc[mt][ri] =
                __builtin_amdgcn_mfma_f32_16x16x32_bf16(af, bf[ri + dh], acc[mt][ri], 0, 0, 0);
        }
      }
    }
  }

  float nw = nw_p[0];
  int col = wv * 16 + l15;
  float nz[8];
#pragma unroll
  for (int ri = 0; ri < 8; ++ri)
    nz[ri] = nw * noise[((size_t)n * 64 + r0 + ri) * 64 + col];
#pragma unroll
  for (int mt = 0; mt < 4; ++mt) {
    f32x4 dm4 = *(const f32x4*)(demod + n * 512 + cb * 64 + mt * 16 + lhi * 4);
#pragma unroll
    for (int c = 0; c < 4; ++c) {
      int co = cb * 64 + mt * 16 + lhi * 4 + c;
      float ab2 = act_bias[co];
      float dm = dm4[c];
#pragma unroll
      for (int ri = 0; ri < 8; ++ri) {
        float v = dm * acc[mt][ri][c] + nz[ri] + ab2;
        v = v > 0.f ? v : 0.2f * v;
        out[(((size_t)n * 512 + co) * 64 + (r0 + ri)) * 64 + col] = v;
      }
    }
  }
}

extern "C" void kernel_launch(void* const* d_in, const int* in_sizes, int n_in,
                              void* d_out, int out_size, void* d_ws, size_t ws_size,
                              hipStream_t stream) {
  const float* x     = (const float*)d_in[0];
  const float* style = (const float*)d_in[1];
  const float* noise = (const float*)d_in[2];
  const float* cw    = (const float*)d_in[3];
  const float* mw    = (const float*)d_in[4];
  const float* mb    = (const float*)d_in[5];
  const float* nw    = (const float*)d_in[6];
  const float* ab    = (const float*)d_in[7];
  float* out = (float*)d_out;

  char* ws = (char*)d_ws;
  float* s_buf  = (float*)ws;                            // 16 KB
  float* demod  = (float*)(ws + 16384);                  // 16 KB
  float* wsq    = (float*)(ws + 32768);                  // 1 MB
  unsigned short* Wt = (unsigned short*)(ws + 1081344);  // 4,718,592 B
  unsigned short* Xp = (unsigned short*)(ws + 5799936);  // 35,684,352 B (end 41.5 MB)

  k_pre<<<2048, 256, 0, stream>>>(style, mw, mb, cw, s_buf, wsq);
  k_mid<<<1800, 256, 0, stream>>>(s_buf, wsq, x, cw, demod, Xp, Wt);
  k_conv<<<dim3(8, 8, 8), 256, 0, stream>>>(Wt, Xp, demod, noise, nw, ab, out);
}